// Round 10
// baseline (110.079 us; speedup 1.0000x reference)
//
#include <hip/hip_runtime.h>
#include <hip/hip_bf16.h>

// Problem constants
#define BB 32
#define GG 1024
#define VV 10000
#define KHID 1024
#define MM 128
#define NCHUNK 625   // 625 * 16 = 10000 rows exactly
#define GEMM_GRID 256

typedef __attribute__((ext_vector_type(8))) short short8;
typedef __attribute__((ext_vector_type(4))) float f32x4;

// pack 2 f32 -> 1 u32 of 2 bf16 (RNE); compiler emits v_cvt_pk_bf16_f32
__device__ __forceinline__ unsigned int pk2(float lo, float hi) {
    __hip_bfloat162 h = __float22bfloat162_rn(make_float2(lo, hi));
    union { __hip_bfloat162 h; unsigned int u; } cv; cv.h = h;
    return cv.u;
}

// bf16 bits -> f32
__device__ __forceinline__ float bfu(unsigned short u) {
    union { unsigned int u; float f; } v; v.u = (unsigned int)u << 16;
    return v.f;
}

// LDS-only barrier: wait local (LDS) ops, then raw s_barrier.
// Does NOT drain vmcnt -> global prefetch loads stay in flight.
__device__ __forceinline__ void lds_barrier() {
    asm volatile("s_waitcnt lgkmcnt(0)" ::: "memory");
    __builtin_amdgcn_s_barrier();
    asm volatile("" ::: "memory");
}

// ---------------------------------------------------------------------------
// K1: T(bf16) = A @ Wg. IDENTICAL to round 8 (best measured). Launched 5x
// this round purely to measure its per-launch cost by subtraction vs r8.
// ---------------------------------------------------------------------------
__global__ __launch_bounds__(512, 2) void k_gemm(const float* __restrict__ A,
                                                 const float* __restrict__ Wfc,
                                                 unsigned short* __restrict__ T) {
    const int tid = threadIdx.x;
    const int w = tid >> 6, lane = tid & 63;
    const int r16 = lane & 15, g = lane >> 4;
    const int kbase = w * 128;

    int chunk = blockIdx.x;

    // issue first chunk's A loads ASAP (fly under the B prologue)
    float4 a[8];
    {
        const float* Ap = A + (size_t)(chunk * 16 + r16) * KHID + kbase + g * 8;
#pragma unroll
        for (int kt = 0; kt < 4; ++kt) {
            a[2 * kt]     = *(const float4*)(Ap + kt * 32);
            a[2 * kt + 1] = *(const float4*)(Ap + kt * 32 + 4);
        }
    }

    // prologue: build B fragment regs from f32 W (second-half rows), transposed
    const float* Wg = Wfc + (size_t)KHID * MM;
    short8 breg[4][8];
#pragma unroll
    for (int kt = 0; kt < 4; ++kt)
#pragma unroll
        for (int t = 0; t < 8; ++t) {
            const float* wp = Wg + (size_t)(kbase + kt * 32 + g * 8) * MM + t * 16 + r16;
            unsigned int* bu = (unsigned int*)&breg[kt][t];
            bu[0] = pk2(wp[0 * MM], wp[1 * MM]);
            bu[1] = pk2(wp[2 * MM], wp[3 * MM]);
            bu[2] = pk2(wp[4 * MM], wp[5 * MM]);
            bu[3] = pk2(wp[6 * MM], wp[7 * MM]);
        }

    __shared__ float red[4][16][132];  // padded: conflict-light

    const int orow = tid >> 5, c4 = (tid & 31) * 4;  // store mapping

    while (chunk < NCHUNK) {
        const int next = chunk + GEMM_GRID;

        // MFMA phase: consume a[] (after this, a[] is dead -> reuse for prefetch)
        f32x4 acc[8];
#pragma unroll
        for (int t = 0; t < 8; ++t) acc[t] = (f32x4){0.f, 0.f, 0.f, 0.f};
#pragma unroll
        for (int kt = 0; kt < 4; ++kt) {
            short8 af;
            unsigned int* au = (unsigned int*)&af;
            au[0] = pk2(a[2 * kt].x, a[2 * kt].y);
            au[1] = pk2(a[2 * kt].z, a[2 * kt].w);
            au[2] = pk2(a[2 * kt + 1].x, a[2 * kt + 1].y);
            au[3] = pk2(a[2 * kt + 1].z, a[2 * kt + 1].w);
#pragma unroll
            for (int t = 0; t < 8; ++t)
                acc[t] = __builtin_amdgcn_mfma_f32_16x16x32_bf16(af, breg[kt][t], acc[t],
                                                                 0, 0, 0);
        }

        // prefetch next chunk's A (in flight across the LDS phases below)
        if (next < NCHUNK) {
            const float* Ap = A + (size_t)(next * 16 + r16) * KHID + kbase + g * 8;
#pragma unroll
            for (int kt = 0; kt < 4; ++kt) {
                a[2 * kt]     = *(const float4*)(Ap + kt * 32);
                a[2 * kt + 1] = *(const float4*)(Ap + kt * 32 + 4);
            }
        }

        // cross-wave K reduction (LDS-only barriers; vmcnt untouched)
        if (w >= 4) {
#pragma unroll
            for (int t = 0; t < 8; ++t)
#pragma unroll
                for (int r = 0; r < 4; ++r)
                    red[w - 4][g * 4 + r][t * 16 + r16] = acc[t][r];
        }
        lds_barrier();
        if (w < 4) {
#pragma unroll
            for (int t = 0; t < 8; ++t)
#pragma unroll
                for (int r = 0; r < 4; ++r)
                    red[w][g * 4 + r][t * 16 + r16] += acc[t][r];
        }
        lds_barrier();

        float sx[4];
#pragma unroll
        for (int j = 0; j < 4; ++j)
            sx[j] = red[0][orow][c4 + j] + red[1][orow][c4 + j] +
                    red[2][orow][c4 + j] + red[3][orow][c4 + j];
        *(uint2*)&T[(size_t)(chunk * 16 + orow) * MM + c4] =
            make_uint2(pk2(sx[0], sx[1]), pk2(sx[2], sx[3]));
        lds_barrier();  // red reused next chunk

        chunk = next;
    }
}

// ---------------------------------------------------------------------------
// K2: partial BN stats over G per (b, chunk of 64 g): grid (16, 32).
// ---------------------------------------------------------------------------
__global__ __launch_bounds__(256) void k_stats(const unsigned short* __restrict__ T,
                                               const int* __restrict__ gPos,
                                               float* __restrict__ ps1,
                                               float* __restrict__ ps2) {
    const int b = blockIdx.y, c = blockIdx.x;
    const int tid = threadIdx.x;

    __shared__ int posl[64];
    __shared__ float r1[4][128], r2[4][128];

    if (tid < 64) posl[tid] = gPos[b * GG + c * 64 + tid];
    __syncthreads();

    const int m = tid & 63, q = tid >> 6;
    float s1a = 0.f, s1b = 0.f, s2a = 0.f, s2b = 0.f;
    for (int g = q; g < 64; g += 4) {
        unsigned int u = *(const unsigned int*)&T[(size_t)posl[g] * MM + m * 2];
        float t0 = bfu((unsigned short)(u & 0xFFFFu));
        float t1 = bfu((unsigned short)(u >> 16));
        s1a += t0; s2a += t0 * t0;
        s1b += t1; s2b += t1 * t1;
    }
    r1[q][m * 2] = s1a; r1[q][m * 2 + 1] = s1b;
    r2[q][m * 2] = s2a; r2[q][m * 2 + 1] = s2b;
    __syncthreads();
    if (tid < 128) {
        ps1[(size_t)(b * 16 + c) * MM + tid] = r1[0][tid] + r1[1][tid] + r1[2][tid] + r1[3][tid];
        ps2[(size_t)(b * 16 + c) * MM + tid] = r2[0][tid] + r2[1][tid] + r2[2][tid] + r2[3][tid];
    }
}

// ---------------------------------------------------------------------------
// K3: final (combine fused): scale/shift from partials, then
// out[b,g] = sigmoid( sum_m relu(scale*T+shift) * W2[m] + b2 ).  grid (16,32)
// ---------------------------------------------------------------------------
__global__ __launch_bounds__(256) void k_final(const unsigned short* __restrict__ T,
                                               const int* __restrict__ gPos,
                                               const float* __restrict__ ps1,
                                               const float* __restrict__ ps2,
                                               const float* __restrict__ gamma,
                                               const float* __restrict__ beta,
                                               const float* __restrict__ W2,
                                               const float* __restrict__ b2,
                                               float* __restrict__ out) {
    const int b = blockIdx.y, gc = blockIdx.x;
    const int tid = threadIdx.x;

    __shared__ float ssc[128], ssh[128];
    __shared__ int posl[64];
    if (tid < 64) posl[tid] = gPos[b * GG + gc * 64 + tid];
    if (tid >= 128 && tid < 256) {
        int mcol = tid - 128;
        float S1 = 0.f, S2 = 0.f;
#pragma unroll
        for (int cc = 0; cc < 16; ++cc) {
            S1 += ps1[(size_t)(b * 16 + cc) * MM + mcol];
            S2 += ps2[(size_t)(b * 16 + cc) * MM + mcol];
        }
        float mean = S1 * (1.f / 1024.f);
        float var  = S2 * (1.f / 1024.f) - mean * mean;
        float rstd = rsqrtf(var + 1e-5f);
        float sc = gamma[mcol] * rstd;
        ssc[mcol] = sc;
        ssh[mcol] = beta[mcol] - sc * mean;
    }
    __syncthreads();

    const int wave = tid >> 6, lane = tid & 63;
    const int m0 = lane * 2, m1 = lane * 2 + 1;
    const float sc0 = ssc[m0], sh0 = ssh[m0], w20 = W2[m0];
    const float sc1 = ssc[m1], sh1 = ssh[m1], w21 = W2[m1];
    const float bias = b2[0];

    for (int i = 0; i < 16; ++i) {
        int gg = wave * 16 + i;
        int pos = posl[gg];
        unsigned int u = *(const unsigned int*)&T[(size_t)pos * MM + m0];
        float t0 = bfu((unsigned short)(u & 0xFFFFu));
        float t1 = bfu((unsigned short)(u >> 16));
        float h0 = fmaxf(sc0 * t0 + sh0, 0.f);
        float h1 = fmaxf(sc1 * t1 + sh1, 0.f);
        float val = h0 * w20 + h1 * w21;
#pragma unroll
        for (int off = 32; off; off >>= 1) val += __shfl_xor(val, off, 64);
        if (lane == 0) out[b * GG + gc * 64 + gg] = 1.f / (1.f + __expf(-(val + bias)));
    }
}

// ---------------------------------------------------------------------------
extern "C" void kernel_launch(void* const* d_in, const int* in_sizes, int n_in,
                              void* d_out, int out_size, void* d_ws, size_t ws_size,
                              hipStream_t stream) {
    const int*   gPos  = (const int*)d_in[3];
    const float* A     = (const float*)d_in[4];
    const float* Wfc   = (const float*)d_in[11];
    const float* gamma = (const float*)d_in[13];
    const float* beta  = (const float*)d_in[14];
    const float* W2    = (const float*)d_in[15];
    const float* b2    = (const float*)d_in[16];
    float* out = (float*)d_out;

    char* ws = (char*)d_ws;
    unsigned short* T = (unsigned short*)ws;        // 2.56 MB bf16
    float* ps1 = (float*)(ws + (4 << 20));          // 256 KB
    float* ps2 = (float*)(ws + (8 << 20));          // 256 KB

    // MEASUREMENT ROUND: k_gemm launched 5x (idempotent -> identical output).
    // gemm_per_launch ~= (total_this_round - 40.7us) / 4
    for (int rep = 0; rep < 5; ++rep)
        hipLaunchKernelGGL(k_gemm, dim3(GEMM_GRID), dim3(512), 0, stream, A, Wfc, T);
    hipLaunchKernelGGL(k_stats, dim3(16, BB), dim3(256), 0, stream, T, gPos, ps1, ps2);
    hipLaunchKernelGGL(k_final, dim3(16, BB), dim3(256), 0, stream, T, gPos, ps1, ps2,
                       gamma, beta, W2, b2, out);
}

// Round 11
// 95.964 us; speedup vs baseline: 1.1471x; 1.1471x over previous
//
#include <hip/hip_runtime.h>
#include <hip/hip_bf16.h>

// Problem constants
#define BB 32
#define GG 1024
#define VV 10000
#define KHID 1024
#define MM 128
#define NCHUNK 625   // 625 * 16 = 10000 rows exactly
#define GEMM_GRID 256

typedef __attribute__((ext_vector_type(8))) short short8;
typedef __attribute__((ext_vector_type(4))) float f32x4;

// f32 -> bf16 bits, round-to-nearest-even (scalar; used in convW)
__device__ __forceinline__ unsigned short bf16_rne(float f) {
    union { float f; unsigned int u; } v; v.f = f;
    unsigned int r = v.u + 0x7FFFu + ((v.u >> 16) & 1u);
    return (unsigned short)(r >> 16);
}

// pack 2 f32 -> 1 u32 of 2 bf16 (RNE); compiler emits v_cvt_pk_bf16_f32
__device__ __forceinline__ unsigned int pk2(float lo, float hi) {
    __hip_bfloat162 h = __float22bfloat162_rn(make_float2(lo, hi));
    union { __hip_bfloat162 h; unsigned int u; } cv; cv.h = h;
    return cv.u;
}

// bf16 bits -> f32
__device__ __forceinline__ float bfu(unsigned short u) {
    union { unsigned int u; float f; } v; v.u = (unsigned int)u << 16;
    return v.f;
}

// LDS-only barrier: wait local (LDS) ops, then raw s_barrier.
// Does NOT drain vmcnt -> global prefetch loads stay in flight.
__device__ __forceinline__ void lds_barrier() {
    asm volatile("s_waitcnt lgkmcnt(0)" ::: "memory");
    __builtin_amdgcn_s_barrier();
    asm volatile("" ::: "memory");
}

// ---------------------------------------------------------------------------
// K0: WtB[col][k] = bf16(W_fc[HID + k][col])  (transpose+convert, LDS-tiled)
// Coalesced loads (c contiguous) and coalesced stores (kk contiguous).
// ---------------------------------------------------------------------------
__global__ __launch_bounds__(256) void k_convW(const float* __restrict__ Wfc,
                                               unsigned short* __restrict__ WtB) {
    __shared__ float Lt[64][33];
    const int k0 = blockIdx.x * 64, c0 = blockIdx.y * 32;
    const int tid = threadIdx.x;
    const float* Wg = Wfc + (size_t)KHID * MM;  // second-half rows of W_fc
#pragma unroll
    for (int i = 0; i < 8; ++i) {
        int idx = tid + i * 256;
        int kk = idx >> 5, c = idx & 31;
        Lt[kk][c] = Wg[(size_t)(k0 + kk) * MM + c0 + c];
    }
    __syncthreads();
#pragma unroll
    for (int i = 0; i < 8; ++i) {
        int idx = tid + i * 256;
        int c = idx >> 6, kk = idx & 63;
        WtB[(size_t)(c0 + c) * KHID + k0 + kk] = bf16_rne(Lt[kk][c]);
    }
}

// ---------------------------------------------------------------------------
// K1: T(bf16) = A @ Wg. r8's pipelined persistent structure (256 blocks x
// 512 thr, 8 waves, K=128/wave, raw barriers, cross-chunk A prefetch) with
// ONE change: B prologue loads coalesced short8 from WtB[col][k] (16 cache
// lines/instr, 64 instrs/wave) instead of 256 strided f32 loads (64 lines
// each) -- removes the ~13 us L1-transaction storm at block start.
// ---------------------------------------------------------------------------
__global__ __launch_bounds__(512, 2) void k_gemm(const float* __restrict__ A,
                                                 const unsigned short* __restrict__ WtB,
                                                 unsigned short* __restrict__ T) {
    const int tid = threadIdx.x;
    const int w = tid >> 6, lane = tid & 63;
    const int r16 = lane & 15, g = lane >> 4;
    const int kbase = w * 128;

    int chunk = blockIdx.x;

    // issue first chunk's A loads ASAP (fly under the B prologue)
    float4 a[8];
    {
        const float* Ap = A + (size_t)(chunk * 16 + r16) * KHID + kbase + g * 8;
#pragma unroll
        for (int kt = 0; kt < 4; ++kt) {
            a[2 * kt]     = *(const float4*)(Ap + kt * 32);
            a[2 * kt + 1] = *(const float4*)(Ap + kt * 32 + 4);
        }
    }

    // B prologue: coalesced bf16 fragment loads (r5's verified pattern)
    const unsigned short* Bp = WtB + (size_t)r16 * KHID + kbase + g * 8;
    short8 breg[4][8];
#pragma unroll
    for (int kt = 0; kt < 4; ++kt)
#pragma unroll
        for (int t = 0; t < 8; ++t)
            breg[kt][t] = *(const short8*)(Bp + (size_t)t * 16 * KHID + kt * 32);

    __shared__ float red[4][16][132];  // padded: conflict-light

    const int orow = tid >> 5, c4 = (tid & 31) * 4;  // store mapping

    while (chunk < NCHUNK) {
        const int next = chunk + GEMM_GRID;

        // MFMA phase: consume a[] (after this, a[] is dead -> reuse for prefetch)
        f32x4 acc[8];
#pragma unroll
        for (int t = 0; t < 8; ++t) acc[t] = (f32x4){0.f, 0.f, 0.f, 0.f};
#pragma unroll
        for (int kt = 0; kt < 4; ++kt) {
            short8 af;
            unsigned int* au = (unsigned int*)&af;
            au[0] = pk2(a[2 * kt].x, a[2 * kt].y);
            au[1] = pk2(a[2 * kt].z, a[2 * kt].w);
            au[2] = pk2(a[2 * kt + 1].x, a[2 * kt + 1].y);
            au[3] = pk2(a[2 * kt + 1].z, a[2 * kt + 1].w);
#pragma unroll
            for (int t = 0; t < 8; ++t)
                acc[t] = __builtin_amdgcn_mfma_f32_16x16x32_bf16(af, breg[kt][t], acc[t],
                                                                 0, 0, 0);
        }

        // prefetch next chunk's A (in flight across the LDS phases below)
        if (next < NCHUNK) {
            const float* Ap = A + (size_t)(next * 16 + r16) * KHID + kbase + g * 8;
#pragma unroll
            for (int kt = 0; kt < 4; ++kt) {
                a[2 * kt]     = *(const float4*)(Ap + kt * 32);
                a[2 * kt + 1] = *(const float4*)(Ap + kt * 32 + 4);
            }
        }

        // cross-wave K reduction (LDS-only barriers; vmcnt untouched)
        if (w >= 4) {
#pragma unroll
            for (int t = 0; t < 8; ++t)
#pragma unroll
                for (int r = 0; r < 4; ++r)
                    red[w - 4][g * 4 + r][t * 16 + r16] = acc[t][r];
        }
        lds_barrier();
        if (w < 4) {
#pragma unroll
            for (int t = 0; t < 8; ++t)
#pragma unroll
                for (int r = 0; r < 4; ++r)
                    red[w][g * 4 + r][t * 16 + r16] += acc[t][r];
        }
        lds_barrier();

        float sx[4];
#pragma unroll
        for (int j = 0; j < 4; ++j)
            sx[j] = red[0][orow][c4 + j] + red[1][orow][c4 + j] +
                    red[2][orow][c4 + j] + red[3][orow][c4 + j];
        *(uint2*)&T[(size_t)(chunk * 16 + orow) * MM + c4] =
            make_uint2(pk2(sx[0], sx[1]), pk2(sx[2], sx[3]));
        lds_barrier();  // red reused next chunk

        chunk = next;
    }
}

// ---------------------------------------------------------------------------
// K2: fused tail, ONE block per batch b (grid 32, 512 thr = 8 waves).
// Phase A: wave w gathers rows g=[w*128,+128), lane covers cols (2l,2l+1),
//          block-reduce -> BN scale/shift in LDS (all intra-block, no coop).
// Phase B: same rows re-gathered (L2-hot), relu-dot -> sigmoid -> out.
// ---------------------------------------------------------------------------
__global__ __launch_bounds__(512) void k_tail2(const unsigned short* __restrict__ T,
                                               const int* __restrict__ gPos,
                                               const float* __restrict__ gamma,
                                               const float* __restrict__ beta,
                                               const float* __restrict__ W2,
                                               const float* __restrict__ b2,
                                               float* __restrict__ out) {
    const int b = blockIdx.x;
    const int tid = threadIdx.x;
    const int w = tid >> 6, lane = tid & 63;

    __shared__ int posl[1024];
    __shared__ float r1[8][128], r2[8][128];
    __shared__ float ssc[128], ssh[128];

    posl[tid]       = gPos[b * GG + tid];
    posl[tid + 512] = gPos[b * GG + tid + 512];
    __syncthreads();

    // phase A: stats
    float s1a = 0.f, s1b = 0.f, s2a = 0.f, s2b = 0.f;
#pragma unroll 4
    for (int i = 0; i < 128; ++i) {
        int pos = posl[w * 128 + i];
        unsigned int u = *(const unsigned int*)&T[(size_t)pos * MM + lane * 2];
        float t0 = bfu((unsigned short)(u & 0xFFFFu));
        float t1 = bfu((unsigned short)(u >> 16));
        s1a += t0; s2a += t0 * t0;
        s1b += t1; s2b += t1 * t1;
    }
    r1[w][lane * 2] = s1a; r1[w][lane * 2 + 1] = s1b;
    r2[w][lane * 2] = s2a; r2[w][lane * 2 + 1] = s2b;
    __syncthreads();

    if (tid < 128) {
        float S1 = 0.f, S2 = 0.f;
#pragma unroll
        for (int q = 0; q < 8; ++q) { S1 += r1[q][tid]; S2 += r2[q][tid]; }
        float mean = S1 * (1.f / 1024.f);
        float var  = S2 * (1.f / 1024.f) - mean * mean;
        float rstd = rsqrtf(var + 1e-5f);
        float sc = gamma[tid] * rstd;
        ssc[tid] = sc;
        ssh[tid] = beta[tid] - sc * mean;
    }
    __syncthreads();

    // phase B: final dot (rows L2-hot from phase A)
    const float sc0 = ssc[lane * 2], sh0 = ssh[lane * 2], w20 = W2[lane * 2];
    const float sc1 = ssc[lane * 2 + 1], sh1 = ssh[lane * 2 + 1], w21 = W2[lane * 2 + 1];
    const float bias = b2[0];

#pragma unroll 2
    for (int i = 0; i < 128; ++i) {
        int g = w * 128 + i;
        int pos = posl[g];
        unsigned int u = *(const unsigned int*)&T[(size_t)pos * MM + lane * 2];
        float t0 = bfu((unsigned short)(u & 0xFFFFu));
        float t1 = bfu((unsigned short)(u >> 16));
        float val = fmaxf(sc0 * t0 + sh0, 0.f) * w20 + fmaxf(sc1 * t1 + sh1, 0.f) * w21;
#pragma unroll
        for (int off = 32; off; off >>= 1) val += __shfl_xor(val, off, 64);
        if (lane == 0) out[b * GG + g] = 1.f / (1.f + __expf(-(val + bias)));
    }
}

// ---------------------------------------------------------------------------
extern "C" void kernel_launch(void* const* d_in, const int* in_sizes, int n_in,
                              void* d_out, int out_size, void* d_ws, size_t ws_size,
                              hipStream_t stream) {
    const int*   gPos  = (const int*)d_in[3];
    const float* A     = (const float*)d_in[4];
    const float* Wfc   = (const float*)d_in[11];
    const float* gamma = (const float*)d_in[13];
    const float* beta  = (const float*)d_in[14];
    const float* W2    = (const float*)d_in[15];
    const float* b2    = (const float*)d_in[16];
    float* out = (float*)d_out;

    char* ws = (char*)d_ws;
    unsigned short* T   = (unsigned short*)ws;               // 2.56 MB bf16
    unsigned short* WtB = (unsigned short*)(ws + (4 << 20)); // 256 KB bf16

    hipLaunchKernelGGL(k_convW, dim3(16, 4), dim3(256), 0, stream, Wfc, WtB);
    hipLaunchKernelGGL(k_gemm, dim3(GEMM_GRID), dim3(512), 0, stream, A, WtB, T);
    hipLaunchKernelGGL(k_tail2, dim3(BB), dim3(512), 0, stream, T, gPos,
                       gamma, beta, W2, b2, out);
}

// Round 12
// 34.684 us; speedup vs baseline: 3.1738x; 2.7668x over previous
//
#include <hip/hip_runtime.h>
#include <hip/hip_bf16.h>

// Problem constants
#define BB 32
#define GG 1024
#define VV 10000
#define KHID 1024
#define MM 128
#define NCHUNK 625   // 625 * 16 = 10000 rows exactly
#define GEMM_GRID 256

typedef __attribute__((ext_vector_type(8))) short short8;
typedef __attribute__((ext_vector_type(4))) float f32x4;

// pack 2 f32 -> 1 u32 of 2 bf16 (RNE); compiler emits v_cvt_pk_bf16_f32
__device__ __forceinline__ unsigned int pk2(float lo, float hi) {
    __hip_bfloat162 h = __float22bfloat162_rn(make_float2(lo, hi));
    union { __hip_bfloat162 h; unsigned int u; } cv; cv.h = h;
    return cv.u;
}

// bf16 bits -> f32
__device__ __forceinline__ float bfu(unsigned short u) {
    union { unsigned int u; float f; } v; v.u = (unsigned int)u << 16;
    return v.f;
}

// LDS-only barrier: wait local (LDS) ops, then raw s_barrier.
// Does NOT drain vmcnt -> global prefetch loads stay in flight.
__device__ __forceinline__ void lds_barrier() {
    asm volatile("s_waitcnt lgkmcnt(0)" ::: "memory");
    __builtin_amdgcn_s_barrier();
    asm volatile("" ::: "memory");
}

// ---------------------------------------------------------------------------
// K1: T(bf16) = A @ Wg. EXACT r8 structure (measured 17.35 us/launch):
// persistent 256 blocks x 512 thr, 8 waves, K=128/wave, fused f32 B-prologue,
// cross-chunk A prefetch, raw barriers, cross-wave LDS reduce, bf16 store.
// ---------------------------------------------------------------------------
__global__ __launch_bounds__(512, 2) void k_gemm(const float* __restrict__ A,
                                                 const float* __restrict__ Wfc,
                                                 unsigned short* __restrict__ T) {
    const int tid = threadIdx.x;
    const int w = tid >> 6, lane = tid & 63;
    const int r16 = lane & 15, g = lane >> 4;
    const int kbase = w * 128;

    int chunk = blockIdx.x;

    // issue first chunk's A loads ASAP (fly under the B prologue)
    float4 a[8];
    {
        const float* Ap = A + (size_t)(chunk * 16 + r16) * KHID + kbase + g * 8;
#pragma unroll
        for (int kt = 0; kt < 4; ++kt) {
            a[2 * kt]     = *(const float4*)(Ap + kt * 32);
            a[2 * kt + 1] = *(const float4*)(Ap + kt * 32 + 4);
        }
    }

    // prologue: build B fragment regs from f32 W (second-half rows), transposed
    const float* Wg = Wfc + (size_t)KHID * MM;
    short8 breg[4][8];
#pragma unroll
    for (int kt = 0; kt < 4; ++kt)
#pragma unroll
        for (int t = 0; t < 8; ++t) {
            const float* wp = Wg + (size_t)(kbase + kt * 32 + g * 8) * MM + t * 16 + r16;
            unsigned int* bu = (unsigned int*)&breg[kt][t];
            bu[0] = pk2(wp[0 * MM], wp[1 * MM]);
            bu[1] = pk2(wp[2 * MM], wp[3 * MM]);
            bu[2] = pk2(wp[4 * MM], wp[5 * MM]);
            bu[3] = pk2(wp[6 * MM], wp[7 * MM]);
        }

    __shared__ float red[4][16][132];  // padded: conflict-light

    const int orow = tid >> 5, c4 = (tid & 31) * 4;  // store mapping

    while (chunk < NCHUNK) {
        const int next = chunk + GEMM_GRID;

        // MFMA phase: consume a[] (after this, a[] is dead -> reuse for prefetch)
        f32x4 acc[8];
#pragma unroll
        for (int t = 0; t < 8; ++t) acc[t] = (f32x4){0.f, 0.f, 0.f, 0.f};
#pragma unroll
        for (int kt = 0; kt < 4; ++kt) {
            short8 af;
            unsigned int* au = (unsigned int*)&af;
            au[0] = pk2(a[2 * kt].x, a[2 * kt].y);
            au[1] = pk2(a[2 * kt].z, a[2 * kt].w);
            au[2] = pk2(a[2 * kt + 1].x, a[2 * kt + 1].y);
            au[3] = pk2(a[2 * kt + 1].z, a[2 * kt + 1].w);
#pragma unroll
            for (int t = 0; t < 8; ++t)
                acc[t] = __builtin_amdgcn_mfma_f32_16x16x32_bf16(af, breg[kt][t], acc[t],
                                                                 0, 0, 0);
        }

        // prefetch next chunk's A (in flight across the LDS phases below)
        if (next < NCHUNK) {
            const float* Ap = A + (size_t)(next * 16 + r16) * KHID + kbase + g * 8;
#pragma unroll
            for (int kt = 0; kt < 4; ++kt) {
                a[2 * kt]     = *(const float4*)(Ap + kt * 32);
                a[2 * kt + 1] = *(const float4*)(Ap + kt * 32 + 4);
            }
        }

        // cross-wave K reduction (LDS-only barriers; vmcnt untouched)
        if (w >= 4) {
#pragma unroll
            for (int t = 0; t < 8; ++t)
#pragma unroll
                for (int r = 0; r < 4; ++r)
                    red[w - 4][g * 4 + r][t * 16 + r16] = acc[t][r];
        }
        lds_barrier();
        if (w < 4) {
#pragma unroll
            for (int t = 0; t < 8; ++t)
#pragma unroll
                for (int r = 0; r < 4; ++r)
                    red[w][g * 4 + r][t * 16 + r16] += acc[t][r];
        }
        lds_barrier();

        float sx[4];
#pragma unroll
        for (int j = 0; j < 4; ++j)
            sx[j] = red[0][orow][c4 + j] + red[1][orow][c4 + j] +
                    red[2][orow][c4 + j] + red[3][orow][c4 + j];
        *(uint2*)&T[(size_t)(chunk * 16 + orow) * MM + c4] =
            make_uint2(pk2(sx[0], sx[1]), pk2(sx[2], sx[3]));
        lds_barrier();  // red reused next chunk

        chunk = next;
    }
}

// ---------------------------------------------------------------------------
// K2: BN stats, grid (32, 32) = 1024 blocks, 32 g per block.
// Thread (q=tid>>6, m=tid&63) covers cols (2m,2m+1), rows q*8..q*8+7.
// The 8 gather words are preloaded into registers (all 8 loads in flight)
// -- ONE latency round-trip per block instead of a serialized loop.
// ---------------------------------------------------------------------------
__global__ __launch_bounds__(256) void k_stats(const unsigned short* __restrict__ T,
                                               const int* __restrict__ gPos,
                                               float* __restrict__ ps1,
                                               float* __restrict__ ps2) {
    const int b = blockIdx.y, c = blockIdx.x;
    const int tid = threadIdx.x;

    __shared__ int posl[32];
    __shared__ float r1[4][128], r2[4][128];

    if (tid < 32) posl[tid] = gPos[b * GG + c * 32 + tid];
    __syncthreads();

    const int m = tid & 63, q = tid >> 6;
    unsigned int uu[8];
#pragma unroll
    for (int i = 0; i < 8; ++i)
        uu[i] = *(const unsigned int*)&T[(size_t)posl[q * 8 + i] * MM + m * 2];

    float s1a = 0.f, s1b = 0.f, s2a = 0.f, s2b = 0.f;
#pragma unroll
    for (int i = 0; i < 8; ++i) {
        float t0 = bfu((unsigned short)(uu[i] & 0xFFFFu));
        float t1 = bfu((unsigned short)(uu[i] >> 16));
        s1a += t0; s2a += t0 * t0;
        s1b += t1; s2b += t1 * t1;
    }
    r1[q][m * 2] = s1a; r1[q][m * 2 + 1] = s1b;
    r2[q][m * 2] = s2a; r2[q][m * 2 + 1] = s2b;
    __syncthreads();
    if (tid < 128) {
        ps1[((size_t)b * 32 + c) * MM + tid] = r1[0][tid] + r1[1][tid] + r1[2][tid] + r1[3][tid];
        ps2[((size_t)b * 32 + c) * MM + tid] = r2[0][tid] + r2[1][tid] + r2[2][tid] + r2[3][tid];
    }
}

// ---------------------------------------------------------------------------
// K3: final, grid (32, 32), 32 g per block (4 waves x 8 g).
// Waves 2-3 combine the 32 stats partials -> scale/shift (overlapped with
// waves 0-1 idle at the barrier); then all waves do a batched-8 gather and
// 8 shuffle-reduce dots -> sigmoid -> out.
// ---------------------------------------------------------------------------
__global__ __launch_bounds__(256) void k_final(const unsigned short* __restrict__ T,
                                               const int* __restrict__ gPos,
                                               const float* __restrict__ ps1,
                                               const float* __restrict__ ps2,
                                               const float* __restrict__ gamma,
                                               const float* __restrict__ beta,
                                               const float* __restrict__ W2,
                                               const float* __restrict__ b2,
                                               float* __restrict__ out) {
    const int b = blockIdx.y, gc = blockIdx.x;
    const int tid = threadIdx.x;

    __shared__ float ssc[128], ssh[128];
    __shared__ int posl[32];
    if (tid < 32) posl[tid] = gPos[b * GG + gc * 32 + tid];
    if (tid >= 128) {
        int mcol = tid - 128;
        float S1 = 0.f, S2 = 0.f;
#pragma unroll
        for (int cc = 0; cc < 32; ++cc) {
            S1 += ps1[((size_t)b * 32 + cc) * MM + mcol];
            S2 += ps2[((size_t)b * 32 + cc) * MM + mcol];
        }
        float mean = S1 * (1.f / 1024.f);
        float var  = S2 * (1.f / 1024.f) - mean * mean;
        float rstd = rsqrtf(var + 1e-5f);
        float sc = gamma[mcol] * rstd;
        ssc[mcol] = sc;
        ssh[mcol] = beta[mcol] - sc * mean;
    }
    __syncthreads();

    const int wave = tid >> 6, lane = tid & 63;
    const int m0 = lane * 2, m1 = lane * 2 + 1;
    const float sc0 = ssc[m0], sh0 = ssh[m0], w20 = W2[m0];
    const float sc1 = ssc[m1], sh1 = ssh[m1], w21 = W2[m1];
    const float bias = b2[0];

    unsigned int uu[8];
#pragma unroll
    for (int i = 0; i < 8; ++i)
        uu[i] = *(const unsigned int*)&T[(size_t)posl[wave * 8 + i] * MM + m0];

#pragma unroll
    for (int i = 0; i < 8; ++i) {
        float t0 = bfu((unsigned short)(uu[i] & 0xFFFFu));
        float t1 = bfu((unsigned short)(uu[i] >> 16));
        float val = fmaxf(sc0 * t0 + sh0, 0.f) * w20 + fmaxf(sc1 * t1 + sh1, 0.f) * w21;
#pragma unroll
        for (int off = 32; off; off >>= 1) val += __shfl_xor(val, off, 64);
        if (lane == 0)
            out[b * GG + gc * 32 + wave * 8 + i] = 1.f / (1.f + __expf(-(val + bias)));
    }
}

// ---------------------------------------------------------------------------
extern "C" void kernel_launch(void* const* d_in, const int* in_sizes, int n_in,
                              void* d_out, int out_size, void* d_ws, size_t ws_size,
                              hipStream_t stream) {
    const int*   gPos  = (const int*)d_in[3];
    const float* A     = (const float*)d_in[4];
    const float* Wfc   = (const float*)d_in[11];
    const float* gamma = (const float*)d_in[13];
    const float* beta  = (const float*)d_in[14];
    const float* W2    = (const float*)d_in[15];
    const float* b2    = (const float*)d_in[16];
    float* out = (float*)d_out;

    char* ws = (char*)d_ws;
    unsigned short* T = (unsigned short*)ws;        // 2.56 MB bf16
    float* ps1 = (float*)(ws + (4 << 20));          // 512 KB
    float* ps2 = (float*)(ws + (8 << 20));          // 512 KB

    hipLaunchKernelGGL(k_gemm, dim3(GEMM_GRID), dim3(512), 0, stream, A, Wfc, T);
    hipLaunchKernelGGL(k_stats, dim3(32, BB), dim3(256), 0, stream, T, gPos, ps1, ps2);
    hipLaunchKernelGGL(k_final, dim3(32, BB), dim3(256), 0, stream, T, gPos, ps1, ps2,
                       gamma, beta, W2, b2, out);
}